// Round 5
// baseline (339.944 us; speedup 1.0000x reference)
//
#include <hip/hip_runtime.h>
#include <hip/hip_bf16.h>
#include <cstdint>

// ---------------- constants ----------------
#define Bn 2
#define Sn 2048
#define Dn 768
#define Hn 12
#define DKn 64
#define DFn 3072
#define Mrows 4096   // B*S

typedef float f32x4 __attribute__((ext_vector_type(4)));
typedef __bf16 bf16x8 __attribute__((ext_vector_type(8)));
typedef short s16x8 __attribute__((ext_vector_type(8)));
typedef short s16x4 __attribute__((ext_vector_type(4)));

__device__ __forceinline__ f32x4 MFMA(s16x8 a, s16x8 b, f32x4 c) {
  return __builtin_amdgcn_mfma_f32_16x16x32_bf16(
      __builtin_bit_cast(bf16x8, a), __builtin_bit_cast(bf16x8, b), c, 0, 0, 0);
}

__device__ __forceinline__ void g2lds16(const void* g, void* l) {
  __builtin_amdgcn_global_load_lds(
      (__attribute__((address_space(1))) void*)(g),
      (__attribute__((address_space(3))) void*)(l), 16, 0, 0);
}

__device__ __forceinline__ short f2bf(float f) {
  unsigned u = __builtin_bit_cast(unsigned, f);
  unsigned r = (u + 0x7fffu + ((u >> 16) & 1u)) >> 16;
  return (short)r;
}

__device__ __forceinline__ float bf2f(short s) {
  unsigned u = ((unsigned)(unsigned short)s) << 16;
  return __builtin_bit_cast(float, u);
}

#define C1f 0.0120224586f   // 0.125/15*log2(e)
#define C2f 0.0961796722f   // (1/15)*log2(e)
#define C3f -86.5617013f    // -60*log2(e)

// ---------------- bias prep: biasb = bf16(bias*C2), masked -> -1e30 ----------------
__global__ __launch_bounds__(256) void bias_prep(const float* __restrict__ bias,
                                                 short* __restrict__ biasb) {
  int gid = blockIdx.x * 256 + threadIdx.x;
  size_t i8 = (size_t)gid * 8;
  int q = (int)((i8 >> 11) & 2047);
  int k0 = (int)(i8 & 2047);
  f32x4 v0 = *(const f32x4*)(bias + i8);
  f32x4 v1 = *(const f32x4*)(bias + i8 + 4);
  s16x8 o;
#pragma unroll
  for (int j = 0; j < 4; j++) o[j] = (k0 + j <= q) ? f2bf(v0[j] * C2f) : f2bf(-1e30f);
#pragma unroll
  for (int j = 0; j < 4; j++) o[4 + j] = (k0 + 4 + j <= q) ? f2bf(v1[j] * C2f) : f2bf(-1e30f);
  *(s16x8*)(biasb + i8) = o;
}

// ---------------- weight transpose: in (R,C) f32 -> out (C,R) bf16 ----------------
__global__ void wtrans(const float* __restrict__ in, short* __restrict__ out, int R, int C) {
  __shared__ float t[32][33];
  int c0 = blockIdx.x * 32, r0 = blockIdx.y * 32;
  int tx = threadIdx.x, ty = threadIdx.y;  // 32 x 8
#pragma unroll
  for (int i = 0; i < 4; i++) t[ty + i * 8][tx] = in[(size_t)(r0 + ty + i * 8) * C + c0 + tx];
  __syncthreads();
#pragma unroll
  for (int i = 0; i < 4; i++) out[(size_t)(c0 + ty + i * 8) * R + r0 + tx] = f2bf(t[tx][ty + i * 8]);
}

// 3-in-1 transpose for Wq/Wk/Wv -> contiguous wqkv_t
__global__ void wtrans3(const float* __restrict__ Wq, const float* __restrict__ Wk,
                        const float* __restrict__ Wv, short* __restrict__ out) {
  __shared__ float t[32][33];
  int z = blockIdx.z;
  const float* in = (z == 0) ? Wq : (z == 1) ? Wk : Wv;
  short* o = out + (size_t)z * Dn * Dn;
  int c0 = blockIdx.x * 32, r0 = blockIdx.y * 32;
  int tx = threadIdx.x, ty = threadIdx.y;
#pragma unroll
  for (int i = 0; i < 4; i++) t[ty + i * 8][tx] = in[(size_t)(r0 + ty + i * 8) * Dn + c0 + tx];
  __syncthreads();
#pragma unroll
  for (int i = 0; i < 4; i++) o[(size_t)(c0 + ty + i * 8) * Dn + r0 + tx] = f2bf(t[tx][ty + i * 8]);
}

// ---------------- layernorm: x f32 (row of 768) -> h bf16 + h f32 ----------------
__global__ __launch_bounds__(256) void ln_kernel(const float* __restrict__ x,
                                                 const float* __restrict__ g,
                                                 const float* __restrict__ b,
                                                 short* __restrict__ hb,
                                                 float* __restrict__ hf) {
  int row = blockIdx.x;
  const float* xr = x + (size_t)row * Dn;
  int tid = threadIdx.x;
  float v[3];
  float s = 0.f, ss = 0.f;
#pragma unroll
  for (int i = 0; i < 3; i++) {
    v[i] = xr[tid + i * 256];
    s += v[i];
    ss += v[i] * v[i];
  }
#pragma unroll
  for (int m = 1; m < 64; m <<= 1) {
    s += __shfl_xor(s, m);
    ss += __shfl_xor(ss, m);
  }
  __shared__ float red[8];
  int w = tid >> 6, lane = tid & 63;
  if (lane == 0) { red[w] = s; red[4 + w] = ss; }
  __syncthreads();
  s = red[0] + red[1] + red[2] + red[3];
  ss = red[4] + red[5] + red[6] + red[7];
  float mean = s * (1.0f / Dn);
  float var = ss * (1.0f / Dn) - mean * mean;
  float rs = rsqrtf(var + 1e-5f);
#pragma unroll
  for (int i = 0; i < 3; i++) {
    int c = tid + i * 256;
    float h = (v[i] - mean) * rs * g[c] + b[c];
    hb[(size_t)row * Dn + c] = f2bf(h);
    hf[(size_t)row * Dn + c] = h;
  }
}

// ---------------- 128x128 bf16 GEMM, BK=64, double-buffered, swizzled LDS ----------
// C = A @ Bt^T.  EPI 0: C bf16   EPI 1: gelu -> C bf16   EPI 2: Cf = acc + addm (f32)
template <int EPI>
__global__ __launch_bounds__(256, 2) void gemm_bt(const short* __restrict__ A,
                                                  const short* __restrict__ Bt,
                                                  short* __restrict__ Cb,
                                                  const float* __restrict__ addm,
                                                  float* __restrict__ Cf,
                                                  int M, int N, int K) {
  __shared__ __align__(16) short As[2][8192];
  __shared__ __align__(16) short Bs[2][8192];
  int tid = threadIdx.x, lane = tid & 63, w = tid >> 6, g = lane >> 4, lt = lane & 15;
  int wr = w >> 1, wc = w & 1;
  int m0 = blockIdx.x * 128, n0 = blockIdx.y * 128;
  // staging: chunk i = h*256+tid -> tile row i>>3, swizzled src k-chunk (i&7)^(row&7)
  int r0 = tid >> 3, c8 = tid & 7;
  const short* Ags[4];
  const short* Bgs[4];
#pragma unroll
  for (int h = 0; h < 4; h++) {
    int row = h * 32 + r0;
    int cc = c8 ^ (row & 7);
    Ags[h] = A + (size_t)(m0 + row) * K + cc * 8;
    Bgs[h] = Bt + (size_t)(n0 + row) * K + cc * 8;
  }
  int sw = lt & 7;
  int ch0 = (g ^ sw) * 8, ch1 = ((4 + g) ^ sw) * 8;
  f32x4 acc[4][4] = {};
  // prologue
#pragma unroll
  for (int h = 0; h < 4; h++) {
    g2lds16(Ags[h], &As[0][(h * 256 + tid) * 8]);
    g2lds16(Bgs[h], &Bs[0][(h * 256 + tid) * 8]);
  }
  __syncthreads();
  int nsteps = K >> 6;
  for (int t = 0; t < nsteps; t++) {
    int cur = t & 1;
    if (t + 1 < nsteps) {
      int k0 = (t + 1) << 6;
#pragma unroll
      for (int h = 0; h < 4; h++) {
        g2lds16(Ags[h] + k0, &As[cur ^ 1][(h * 256 + tid) * 8]);
        g2lds16(Bgs[h] + k0, &Bs[cur ^ 1][(h * 256 + tid) * 8]);
      }
    }
    s16x8 af[4][2], bf[4][2];
#pragma unroll
    for (int i = 0; i < 4; i++) {
      int row = wr * 64 + i * 16 + lt;
      af[i][0] = *(const s16x8*)&As[cur][row * 64 + ch0];
      af[i][1] = *(const s16x8*)&As[cur][row * 64 + ch1];
    }
#pragma unroll
    for (int i = 0; i < 4; i++) {
      int row = wc * 64 + i * 16 + lt;
      bf[i][0] = *(const s16x8*)&Bs[cur][row * 64 + ch0];
      bf[i][1] = *(const s16x8*)&Bs[cur][row * 64 + ch1];
    }
#pragma unroll
    for (int mi = 0; mi < 4; mi++)
#pragma unroll
      for (int ni = 0; ni < 4; ni++) {
        acc[mi][ni] = MFMA(af[mi][0], bf[ni][0], acc[mi][ni]);
        acc[mi][ni] = MFMA(af[mi][1], bf[ni][1], acc[mi][ni]);
      }
    __syncthreads();
  }
#pragma unroll
  for (int mi = 0; mi < 4; mi++) {
    int m = m0 + wr * 64 + mi * 16 + g * 4;
#pragma unroll
    for (int ni = 0; ni < 4; ni++) {
      int n = n0 + wc * 64 + ni * 16 + lt;
#pragma unroll
      for (int r = 0; r < 4; r++) {
        float v = acc[mi][ni][r];
        size_t idx = (size_t)(m + r) * N + n;
        if constexpr (EPI == 0) {
          Cb[idx] = f2bf(v);
        } else if constexpr (EPI == 1) {
          float ge = 0.5f * v * (1.0f + erff(v * 0.70710678f));
          Cb[idx] = f2bf(ge);
        } else {
          Cf[idx] = v + addm[idx];
        }
      }
    }
  }
}

// ---------------- 64x64-tile bf16 GEMM for skinny-N, double-buffered, swizzled ----
template <int EPI>
__global__ __launch_bounds__(256, 4) void gemm64(const short* __restrict__ A,
                                                 const short* __restrict__ Bt,
                                                 short* __restrict__ Cb,
                                                 const float* __restrict__ addm,
                                                 float* __restrict__ Cf,
                                                 int M, int N, int K) {
  __shared__ __align__(16) short As[2][4096];
  __shared__ __align__(16) short Bs[2][4096];
  int tid = threadIdx.x, lane = tid & 63, w = tid >> 6, g = lane >> 4, lt = lane & 15;
  int wr = w >> 1, wc = w & 1;
  int m0 = blockIdx.x * 64, n0 = blockIdx.y * 64;
  int r0 = tid >> 3, cc = (tid & 7) ^ (r0 & 7);
  const short* asrc0 = A + (size_t)(m0 + r0) * K + cc * 8;
  const short* asrc1 = A + (size_t)(m0 + r0 + 32) * K + cc * 8;
  const short* bsrc0 = Bt + (size_t)(n0 + r0) * K + cc * 8;
  const short* bsrc1 = Bt + (size_t)(n0 + r0 + 32) * K + cc * 8;
  int sw = lt & 7;
  int ch0 = (g ^ sw) * 8, ch1 = ((4 + g) ^ sw) * 8;
  f32x4 acc[2][2] = {};
  g2lds16(asrc0, &As[0][tid * 8]);
  g2lds16(asrc1, &As[0][2048 + tid * 8]);
  g2lds16(bsrc0, &Bs[0][tid * 8]);
  g2lds16(bsrc1, &Bs[0][2048 + tid * 8]);
  __syncthreads();
  int nsteps = K >> 6;
  for (int t = 0; t < nsteps; t++) {
    int cur = t & 1;
    if (t + 1 < nsteps) {
      int k0 = (t + 1) << 6;
      g2lds16(asrc0 + k0, &As[cur ^ 1][tid * 8]);
      g2lds16(asrc1 + k0, &As[cur ^ 1][2048 + tid * 8]);
      g2lds16(bsrc0 + k0, &Bs[cur ^ 1][tid * 8]);
      g2lds16(bsrc1 + k0, &Bs[cur ^ 1][2048 + tid * 8]);
    }
    s16x8 af[2][2], bf[2][2];
#pragma unroll
    for (int mi = 0; mi < 2; mi++) {
      af[mi][0] = *(const s16x8*)&As[cur][(wr * 32 + mi * 16 + lt) * 64 + ch0];
      af[mi][1] = *(const s16x8*)&As[cur][(wr * 32 + mi * 16 + lt) * 64 + ch1];
    }
#pragma unroll
    for (int ni = 0; ni < 2; ni++) {
      bf[ni][0] = *(const s16x8*)&Bs[cur][(wc * 32 + ni * 16 + lt) * 64 + ch0];
      bf[ni][1] = *(const s16x8*)&Bs[cur][(wc * 32 + ni * 16 + lt) * 64 + ch1];
    }
#pragma unroll
    for (int mi = 0; mi < 2; mi++)
#pragma unroll
      for (int ni = 0; ni < 2; ni++) {
        acc[mi][ni] = MFMA(af[mi][0], bf[ni][0], acc[mi][ni]);
        acc[mi][ni] = MFMA(af[mi][1], bf[ni][1], acc[mi][ni]);
      }
    __syncthreads();
  }
#pragma unroll
  for (int mi = 0; mi < 2; mi++) {
    int m = m0 + wr * 32 + mi * 16 + g * 4;
#pragma unroll
    for (int ni = 0; ni < 2; ni++) {
      int n = n0 + wc * 32 + ni * 16 + lt;
#pragma unroll
      for (int r = 0; r < 4; r++) {
        float v = acc[mi][ni][r];
        size_t idx = (size_t)(m + r) * N + n;
        if constexpr (EPI == 0) {
          Cb[idx] = f2bf(v);
        } else if constexpr (EPI == 1) {
          float ge = 0.5f * v * (1.0f + erff(v * 0.70710678f));
          Cb[idx] = f2bf(ge);
        } else {
          Cf[idx] = v + addm[idx];
        }
      }
    }
  }
}

// ---------------- V transpose: qkv v-cols -> vt (B,H,DK,S) bf16 ----------------
__global__ void vtrans(const short* __restrict__ qkv, short* __restrict__ vt) {
  __shared__ short t[32][33];
  int bh = blockIdx.z;
  int b = bh / Hn, h = bh % Hn;
  int s0 = blockIdx.x * 32, d0 = blockIdx.y * 32;
  int tx = threadIdx.x, ty = threadIdx.y;
#pragma unroll
  for (int i = 0; i < 4; i++)
    t[ty + i * 8][tx] =
        qkv[(size_t)(b * Sn + s0 + ty + i * 8) * (3 * Dn) + 2 * Dn + h * DKn + d0 + tx];
  __syncthreads();
#pragma unroll
  for (int i = 0; i < 4; i++)
    vt[(size_t)(bh * DKn + d0 + ty + i * 8) * Sn + s0 + tx] = t[tx][ty + i * 8];
}

// ---------------- fused attention: 64-row Q-tile, LDS K/V dbuf, pipelined bias -----
// Bias is pre-scaled bf16 with mask baked in (-1e30 -> p ~ 1e-26 ~ 0): no cndmask.
// Bias regs for iteration t+1 are loaded during iteration t (latency hidden).
__global__ __launch_bounds__(256, 3) void attn_kernel(const short* __restrict__ qkv,
                                                      const short* __restrict__ vt,
                                                      const short* __restrict__ biasb,
                                                      short* __restrict__ o) {
  __shared__ __align__(16) short Ks[2][4096];
  __shared__ __align__(16) short Vs[2][4096];
  __shared__ __align__(16) short plds[4][16][72];
  int bh = blockIdx.x;
  int by = blockIdx.y;
  int qt = (by & 1) ? (31 - (by >> 1)) : (by >> 1);  // snake: mix long/short blocks
  int b = bh / Hn, h = bh - b * Hn;
  int tid = threadIdx.x, w = tid >> 6, lane = tid & 63, g = lane >> 4, lt = lane & 15;
  int q0 = qt * 64 + w * 16;
  const short* qbase = qkv + (size_t)(b * Sn + q0 + lt) * (3 * Dn) + h * DKn;
  s16x8 qf0 = *(const s16x8*)(qbase + g * 8);
  s16x8 qf1 = *(const s16x8*)(qbase + 32 + g * 8);
  int sr0 = tid >> 3, scc = (tid & 7) ^ (sr0 & 7);
  const short* kseg = qkv + (size_t)b * Sn * (3 * Dn) + Dn + h * DKn;
  const short* ksrc0 = kseg + (size_t)sr0 * (3 * Dn) + scc * 8;
  const short* ksrc1 = kseg + (size_t)(sr0 + 32) * (3 * Dn) + scc * 8;
  const short* vseg = vt + (size_t)bh * DKn * Sn;
  const short* vsrc0 = vseg + (size_t)sr0 * Sn + scc * 8;
  const short* vsrc1 = vseg + (size_t)(sr0 + 32) * Sn + scc * 8;
  int sw = lt & 7;
  int ch0 = (g ^ sw) * 8, ch1 = ((4 + g) ^ sw) * 8;
  const short* bbase = biasb + ((size_t)b * Sn + q0 + g * 4) * Sn + lt;
  f32x4 oacc[4] = {};
  float lsum[4] = {0.f, 0.f, 0.f, 0.f};
  // prologue: stage tile 0 + bias regs for t=0
  g2lds16(ksrc0, &Ks[0][tid * 8]);
  g2lds16(ksrc1, &Ks[0][2048 + tid * 8]);
  g2lds16(vsrc0, &Vs[0][tid * 8]);
  g2lds16(vsrc1, &Vs[0][2048 + tid * 8]);
  short sb[16];
#pragma unroll
  for (int c = 0; c < 4; c++)
#pragma unroll
    for (int r = 0; r < 4; r++) sb[c * 4 + r] = bbase[(size_t)r * Sn + c * 16];
  __syncthreads();
  for (int t = 0; t <= qt; t++) {
    int cur = t & 1;
    int kc0 = t * 64;
    if (t < qt) {  // prefetch next K/V tile into other buffer
      size_t koff = (size_t)(kc0 + 64) * (3 * Dn);
      g2lds16(ksrc0 + koff, &Ks[cur ^ 1][tid * 8]);
      g2lds16(ksrc1 + koff, &Ks[cur ^ 1][2048 + tid * 8]);
      g2lds16(vsrc0 + kc0 + 64, &Vs[cur ^ 1][tid * 8]);
      g2lds16(vsrc1 + kc0 + 64, &Vs[cur ^ 1][2048 + tid * 8]);
    }
    // prefetch bias regs for t+1 (consumed next iteration -> latency hidden)
    short sbn[16];
    if (t < qt) {
      int kn = kc0 + 64;
#pragma unroll
      for (int c = 0; c < 4; c++)
#pragma unroll
        for (int r = 0; r < 4; r++) sbn[c * 4 + r] = bbase[(size_t)r * Sn + kn + c * 16];
    }
    // K fragments from LDS (swizzled)
    s16x8 kf[4][2];
#pragma unroll
    for (int c = 0; c < 4; c++) {
      kf[c][0] = *(const s16x8*)&Ks[cur][(c * 16 + lt) * 64 + ch0];
      kf[c][1] = *(const s16x8*)&Ks[cur][(c * 16 + lt) * 64 + ch1];
    }
    f32x4 s[4] = {};
#pragma unroll
    for (int c = 0; c < 4; c++) {
      s[c] = MFMA(qf0, kf[c][0], s[c]);
      s[c] = MFMA(qf1, kf[c][1], s[c]);
    }
    // V fragments from LDS
    s16x8 vf[4][2];
#pragma unroll
    for (int dt = 0; dt < 4; dt++) {
      vf[dt][0] = *(const s16x8*)&Vs[cur][(dt * 16 + lt) * 64 + ch0];
      vf[dt][1] = *(const s16x8*)&Vs[cur][(dt * 16 + lt) * 64 + ch1];
    }
    // softcap softmax, static max 30: p = exp2(C3 / (1 + exp2(s*C1 + biasb)))
#pragma unroll
    for (int c = 0; c < 4; c++) {
#pragma unroll
      for (int r = 0; r < 4; r++) {
        float targ = fmaf(s[c][r], C1f, bf2f(sb[c * 4 + r]));
        float e = __builtin_amdgcn_exp2f(targ);
        float u = __builtin_amdgcn_rcpf(1.0f + e);
        float p = __builtin_amdgcn_exp2f(C3f * u);
        lsum[r] += p;
        plds[w][g * 4 + r][c * 16 + lt] = f2bf(p);
      }
    }
    // P round-trip (C-layout -> A-layout) and PV
    s16x8 pf0 = *(const s16x8*)&plds[w][lt][g * 8];
    s16x8 pf1 = *(const s16x8*)&plds[w][lt][32 + g * 8];
#pragma unroll
    for (int dt = 0; dt < 4; dt++) {
      oacc[dt] = MFMA(pf0, vf[dt][0], oacc[dt]);
      oacc[dt] = MFMA(pf1, vf[dt][1], oacc[dt]);
    }
    __syncthreads();
    if (t < qt) {
#pragma unroll
      for (int i = 0; i < 16; i++) sb[i] = sbn[i];
    }
  }
  // normalize and store (wave owns its rows completely)
  float inv[4];
#pragma unroll
  for (int r = 0; r < 4; r++) {
    float l = lsum[r];
    l += __shfl_xor(l, 1);
    l += __shfl_xor(l, 2);
    l += __shfl_xor(l, 4);
    l += __shfl_xor(l, 8);
    inv[r] = __builtin_amdgcn_rcpf(l);
  }
  short* obase = o + (size_t)(b * Sn + q0 + g * 4) * Dn + h * DKn + lt;
#pragma unroll
  for (int dt = 0; dt < 4; dt++)
#pragma unroll
    for (int r = 0; r < 4; r++) obase[(size_t)r * Dn + dt * 16] = f2bf(oacc[dt][r] * inv[r]);
}

// ---------------- launch ----------------
extern "C" void kernel_launch(void* const* d_in, const int* in_sizes, int n_in,
                              void* d_out, int out_size, void* d_ws, size_t ws_size,
                              hipStream_t stream) {
  const float* x = (const float*)d_in[0];
  const float* bias = (const float*)d_in[1];
  // d_in[2] = attn_mask (exact causal tril) -> baked into biasb
  const float* Wq = (const float*)d_in[3];
  const float* Wk = (const float*)d_in[4];
  const float* Wv = (const float*)d_in[5];
  const float* Wo = (const float*)d_in[6];
  const float* W1 = (const float*)d_in[7];
  const float* W2 = (const float*)d_in[8];
  const float* g1 = (const float*)d_in[9];
  const float* b1 = (const float*)d_in[10];
  const float* g2 = (const float*)d_in[11];
  const float* b2 = (const float*)d_in[12];
  float* out = (float*)d_out;
  char* ws = (char*)d_ws;

  short* wqkv_t = (short*)(ws + 0);          // 2304x768 bf16
  short* wo_t = (short*)(ws + 3538944);      // 768x768
  short* w1_t = (short*)(ws + 4718592);      // 3072x768
  short* w2_t = (short*)(ws + 9437184);      // 768x3072
  short* hb = (short*)(ws + 14155776);       // 4096x768 bf16 (reused as h2b)
  float* hf = (float*)(ws + 20447232);       // 4096x768 f32  (reused as h2f)
  short* qkv = (short*)(ws + 33030144);      // 4096x2304 bf16 (region reused by a1)
  short* a1 = qkv;
  short* vt = (short*)(ws + 58195968);       // 24x64x2048 bf16 (region reused by x1 f32)
  float* x1 = (float*)(ws + 58195968);
  short* o_ = (short*)(ws + 70778880);       // 4096x768 bf16
  short* biasb = (short*)(ws + 77070336);    // 2x2048x2048 bf16 (masked, pre-scaled)
  short* h2b = hb;
  float* h2f = hf;

  dim3 tb(32, 8);
  bias_prep<<<4096, 256, 0, stream>>>(bias, biasb);
  wtrans3<<<dim3(24, 24, 3), tb, 0, stream>>>(Wq, Wk, Wv, wqkv_t);
  wtrans<<<dim3(24, 24), tb, 0, stream>>>(Wo, wo_t, Dn, Dn);
  wtrans<<<dim3(96, 24), tb, 0, stream>>>(W1, w1_t, Dn, DFn);
  wtrans<<<dim3(24, 96), tb, 0, stream>>>(W2, w2_t, DFn, Dn);

  ln_kernel<<<Mrows, 256, 0, stream>>>(x, g1, b1, hb, hf);

  gemm_bt<0><<<dim3(32, 18), 256, 0, stream>>>(hb, wqkv_t, qkv, nullptr, nullptr,
                                               Mrows, 3 * Dn, Dn);
  vtrans<<<dim3(64, 2, Bn * Hn), tb, 0, stream>>>(qkv, vt);
  attn_kernel<<<dim3(24, 32), 256, 0, stream>>>(qkv, vt, biasb, o_);

  gemm64<2><<<dim3(64, 12), 256, 0, stream>>>(o_, wo_t, nullptr, hf, x1,
                                              Mrows, Dn, Dn);
  ln_kernel<<<Mrows, 256, 0, stream>>>(x1, g2, b2, h2b, h2f);
  gemm_bt<1><<<dim3(32, 24), 256, 0, stream>>>(h2b, w1_t, a1, nullptr, nullptr,
                                               Mrows, DFn, Dn);
  gemm64<2><<<dim3(64, 12), 256, 0, stream>>>(a1, w2_t, nullptr, h2f, out,
                                              Mrows, Dn, DFn);
}

// Round 6
// 338.992 us; speedup vs baseline: 1.0028x; 1.0028x over previous
//
#include <hip/hip_runtime.h>
#include <hip/hip_bf16.h>
#include <cstdint>

// ---------------- constants ----------------
#define Bn 2
#define Sn 2048
#define Dn 768
#define Hn 12
#define DKn 64
#define DFn 3072
#define Mrows 4096   // B*S

typedef float f32x4 __attribute__((ext_vector_type(4)));
typedef __bf16 bf16x8 __attribute__((ext_vector_type(8)));
typedef short s16x8 __attribute__((ext_vector_type(8)));
typedef short s16x4 __attribute__((ext_vector_type(4)));

__device__ __forceinline__ f32x4 MFMA(s16x8 a, s16x8 b, f32x4 c) {
  return __builtin_amdgcn_mfma_f32_16x16x32_bf16(
      __builtin_bit_cast(bf16x8, a), __builtin_bit_cast(bf16x8, b), c, 0, 0, 0);
}

__device__ __forceinline__ void g2lds16(const void* g, void* l) {
  __builtin_amdgcn_global_load_lds(
      (__attribute__((address_space(1))) void*)(g),
      (__attribute__((address_space(3))) void*)(l), 16, 0, 0);
}

__device__ __forceinline__ short f2bf(float f) {
  unsigned u = __builtin_bit_cast(unsigned, f);
  unsigned r = (u + 0x7fffu + ((u >> 16) & 1u)) >> 16;
  return (short)r;
}

__device__ __forceinline__ float bf2f(short s) {
  unsigned u = ((unsigned)(unsigned short)s) << 16;
  return __builtin_bit_cast(float, u);
}

#define C1f 0.0120224586f   // 0.125/15*log2(e)
#define C2f 0.0961796722f   // (1/15)*log2(e)
#define C3f -86.5617013f    // -60*log2(e)

// ---------------- bias prep: biasb = bf16(bias*C2), masked -> -1e30 ----------------
__global__ __launch_bounds__(256) void bias_prep(const float* __restrict__ bias,
                                                 short* __restrict__ biasb) {
  int gid = blockIdx.x * 256 + threadIdx.x;
  size_t i8 = (size_t)gid * 8;
  int q = (int)((i8 >> 11) & 2047);
  int k0 = (int)(i8 & 2047);
  f32x4 v0 = *(const f32x4*)(bias + i8);
  f32x4 v1 = *(const f32x4*)(bias + i8 + 4);
  s16x8 o;
#pragma unroll
  for (int j = 0; j < 4; j++) o[j] = (k0 + j <= q) ? f2bf(v0[j] * C2f) : f2bf(-1e30f);
#pragma unroll
  for (int j = 0; j < 4; j++) o[4 + j] = (k0 + 4 + j <= q) ? f2bf(v1[j] * C2f) : f2bf(-1e30f);
  *(s16x8*)(biasb + i8) = o;
}

// ---------------- weight transpose: in (R,C) f32 -> out (C,R) bf16 ----------------
__global__ void wtrans(const float* __restrict__ in, short* __restrict__ out, int R, int C) {
  __shared__ float t[32][33];
  int c0 = blockIdx.x * 32, r0 = blockIdx.y * 32;
  int tx = threadIdx.x, ty = threadIdx.y;  // 32 x 8
#pragma unroll
  for (int i = 0; i < 4; i++) t[ty + i * 8][tx] = in[(size_t)(r0 + ty + i * 8) * C + c0 + tx];
  __syncthreads();
#pragma unroll
  for (int i = 0; i < 4; i++) out[(size_t)(c0 + ty + i * 8) * R + r0 + tx] = f2bf(t[tx][ty + i * 8]);
}

// 3-in-1 transpose for Wq/Wk/Wv -> contiguous wqkv_t
__global__ void wtrans3(const float* __restrict__ Wq, const float* __restrict__ Wk,
                        const float* __restrict__ Wv, short* __restrict__ out) {
  __shared__ float t[32][33];
  int z = blockIdx.z;
  const float* in = (z == 0) ? Wq : (z == 1) ? Wk : Wv;
  short* o = out + (size_t)z * Dn * Dn;
  int c0 = blockIdx.x * 32, r0 = blockIdx.y * 32;
  int tx = threadIdx.x, ty = threadIdx.y;
#pragma unroll
  for (int i = 0; i < 4; i++) t[ty + i * 8][tx] = in[(size_t)(r0 + ty + i * 8) * Dn + c0 + tx];
  __syncthreads();
#pragma unroll
  for (int i = 0; i < 4; i++) o[(size_t)(c0 + ty + i * 8) * Dn + r0 + tx] = f2bf(t[tx][ty + i * 8]);
}

// ---------------- layernorm: x f32 (row of 768) -> h bf16 + h f32 ----------------
__global__ __launch_bounds__(256) void ln_kernel(const float* __restrict__ x,
                                                 const float* __restrict__ g,
                                                 const float* __restrict__ b,
                                                 short* __restrict__ hb,
                                                 float* __restrict__ hf) {
  int row = blockIdx.x;
  const float* xr = x + (size_t)row * Dn;
  int tid = threadIdx.x;
  float v[3];
  float s = 0.f, ss = 0.f;
#pragma unroll
  for (int i = 0; i < 3; i++) {
    v[i] = xr[tid + i * 256];
    s += v[i];
    ss += v[i] * v[i];
  }
#pragma unroll
  for (int m = 1; m < 64; m <<= 1) {
    s += __shfl_xor(s, m);
    ss += __shfl_xor(ss, m);
  }
  __shared__ float red[8];
  int w = tid >> 6, lane = tid & 63;
  if (lane == 0) { red[w] = s; red[4 + w] = ss; }
  __syncthreads();
  s = red[0] + red[1] + red[2] + red[3];
  ss = red[4] + red[5] + red[6] + red[7];
  float mean = s * (1.0f / Dn);
  float var = ss * (1.0f / Dn) - mean * mean;
  float rs = rsqrtf(var + 1e-5f);
#pragma unroll
  for (int i = 0; i < 3; i++) {
    int c = tid + i * 256;
    float h = (v[i] - mean) * rs * g[c] + b[c];
    hb[(size_t)row * Dn + c] = f2bf(h);
    hf[(size_t)row * Dn + c] = h;
  }
}

// ---------------- 128x128 bf16 GEMM, BK=32, single-buffer, swizzled LDS -----------
// C = A @ Bt^T.  EPI 0: C bf16   EPI 1: gelu -> C bf16   EPI 2: Cf = acc + addm (f32)
// LDS rows are 32 shorts (64B); chunk swizzle cc = c4 ^ ((row>>1)&3) makes the
// stride-64B fragment reads 2-way (free) instead of 8-way conflicted.
template <int EPI>
__global__ __launch_bounds__(256) void gemm_bt(const short* __restrict__ A,
                                               const short* __restrict__ Bt,
                                               short* __restrict__ Cb,
                                               const float* __restrict__ addm,
                                               float* __restrict__ Cf,
                                               int M, int N, int K) {
  __shared__ __align__(16) short As[4096];
  __shared__ __align__(16) short Bs[4096];
  int tid = threadIdx.x;
  int lane = tid & 63, w = tid >> 6, g = lane >> 4, lt = lane & 15;
  int wr = w >> 1, wc = w & 1;
  int m0 = blockIdx.x * 128, n0 = blockIdx.y * 128;
  // staging: chunk i = h*256+tid -> row i>>2 (h=1: +64), src chunk (i&3)^((row>>1)&3)
  int r0 = tid >> 2, c4 = tid & 3;
  int cc = c4 ^ ((r0 >> 1) & 3);
  const short* Ag0 = A + (size_t)(m0 + r0) * K + cc * 8;
  const short* Ag1 = A + (size_t)(m0 + r0 + 64) * K + cc * 8;
  const short* Bg0 = Bt + (size_t)(n0 + r0) * K + cc * 8;
  const short* Bg1 = Bt + (size_t)(n0 + r0 + 64) * K + cc * 8;
  int swr = (lt >> 1) & 3;
  int cfrag = (g ^ swr) * 8;  // swizzled k-chunk offset (shorts) for fragment reads
  f32x4 acc[4][4] = {};
  for (int k0 = 0; k0 < K; k0 += 32) {
    g2lds16(Ag0 + k0, &As[tid * 8]);
    g2lds16(Ag1 + k0, &As[2048 + tid * 8]);
    g2lds16(Bg0 + k0, &Bs[tid * 8]);
    g2lds16(Bg1 + k0, &Bs[2048 + tid * 8]);
    __syncthreads();
    s16x8 af[4], bfr[4];
#pragma unroll
    for (int i = 0; i < 4; i++) {
      af[i] = *(const s16x8*)&As[(wr * 64 + i * 16 + lt) * 32 + cfrag];
      bfr[i] = *(const s16x8*)&Bs[(wc * 64 + i * 16 + lt) * 32 + cfrag];
    }
#pragma unroll
    for (int mi = 0; mi < 4; mi++)
#pragma unroll
      for (int ni = 0; ni < 4; ni++) acc[mi][ni] = MFMA(af[mi], bfr[ni], acc[mi][ni]);
    __syncthreads();
  }
#pragma unroll
  for (int mi = 0; mi < 4; mi++) {
    int m = m0 + wr * 64 + mi * 16 + g * 4;
#pragma unroll
    for (int ni = 0; ni < 4; ni++) {
      int n = n0 + wc * 64 + ni * 16 + lt;
#pragma unroll
      for (int r = 0; r < 4; r++) {
        float v = acc[mi][ni][r];
        size_t idx = (size_t)(m + r) * N + n;
        if constexpr (EPI == 0) {
          Cb[idx] = f2bf(v);
        } else if constexpr (EPI == 1) {
          float ge = 0.5f * v * (1.0f + erff(v * 0.70710678f));
          Cb[idx] = f2bf(ge);
        } else {
          Cf[idx] = v + addm[idx];
        }
      }
    }
  }
}

// ---------------- 64x64-tile bf16 GEMM for skinny-N, double-buffered, swizzled ----
template <int EPI>
__global__ __launch_bounds__(256, 4) void gemm64(const short* __restrict__ A,
                                                 const short* __restrict__ Bt,
                                                 short* __restrict__ Cb,
                                                 const float* __restrict__ addm,
                                                 float* __restrict__ Cf,
                                                 int M, int N, int K) {
  __shared__ __align__(16) short As[2][4096];
  __shared__ __align__(16) short Bs[2][4096];
  int tid = threadIdx.x, lane = tid & 63, w = tid >> 6, g = lane >> 4, lt = lane & 15;
  int wr = w >> 1, wc = w & 1;
  int m0 = blockIdx.x * 64, n0 = blockIdx.y * 64;
  int r0 = tid >> 3, cc = (tid & 7) ^ (r0 & 7);
  const short* asrc0 = A + (size_t)(m0 + r0) * K + cc * 8;
  const short* asrc1 = A + (size_t)(m0 + r0 + 32) * K + cc * 8;
  const short* bsrc0 = Bt + (size_t)(n0 + r0) * K + cc * 8;
  const short* bsrc1 = Bt + (size_t)(n0 + r0 + 32) * K + cc * 8;
  int sw = lt & 7;
  int ch0 = (g ^ sw) * 8, ch1 = ((4 + g) ^ sw) * 8;
  f32x4 acc[2][2] = {};
  g2lds16(asrc0, &As[0][tid * 8]);
  g2lds16(asrc1, &As[0][2048 + tid * 8]);
  g2lds16(bsrc0, &Bs[0][tid * 8]);
  g2lds16(bsrc1, &Bs[0][2048 + tid * 8]);
  __syncthreads();
  int nsteps = K >> 6;
  for (int t = 0; t < nsteps; t++) {
    int cur = t & 1;
    if (t + 1 < nsteps) {
      int k0 = (t + 1) << 6;
      g2lds16(asrc0 + k0, &As[cur ^ 1][tid * 8]);
      g2lds16(asrc1 + k0, &As[cur ^ 1][2048 + tid * 8]);
      g2lds16(bsrc0 + k0, &Bs[cur ^ 1][tid * 8]);
      g2lds16(bsrc1 + k0, &Bs[cur ^ 1][2048 + tid * 8]);
    }
    s16x8 af[2][2], bf[2][2];
#pragma unroll
    for (int mi = 0; mi < 2; mi++) {
      af[mi][0] = *(const s16x8*)&As[cur][(wr * 32 + mi * 16 + lt) * 64 + ch0];
      af[mi][1] = *(const s16x8*)&As[cur][(wr * 32 + mi * 16 + lt) * 64 + ch1];
    }
#pragma unroll
    for (int ni = 0; ni < 2; ni++) {
      bf[ni][0] = *(const s16x8*)&Bs[cur][(wc * 32 + ni * 16 + lt) * 64 + ch0];
      bf[ni][1] = *(const s16x8*)&Bs[cur][(wc * 32 + ni * 16 + lt) * 64 + ch1];
    }
#pragma unroll
    for (int mi = 0; mi < 2; mi++)
#pragma unroll
      for (int ni = 0; ni < 2; ni++) {
        acc[mi][ni] = MFMA(af[mi][0], bf[ni][0], acc[mi][ni]);
        acc[mi][ni] = MFMA(af[mi][1], bf[ni][1], acc[mi][ni]);
      }
    __syncthreads();
  }
#pragma unroll
  for (int mi = 0; mi < 2; mi++) {
    int m = m0 + wr * 32 + mi * 16 + g * 4;
#pragma unroll
    for (int ni = 0; ni < 2; ni++) {
      int n = n0 + wc * 32 + ni * 16 + lt;
#pragma unroll
      for (int r = 0; r < 4; r++) {
        float v = acc[mi][ni][r];
        size_t idx = (size_t)(m + r) * N + n;
        if constexpr (EPI == 0) {
          Cb[idx] = f2bf(v);
        } else if constexpr (EPI == 1) {
          float ge = 0.5f * v * (1.0f + erff(v * 0.70710678f));
          Cb[idx] = f2bf(ge);
        } else {
          Cf[idx] = v + addm[idx];
        }
      }
    }
  }
}

// ---------------- V transpose: qkv v-cols -> vt (B,H,DK,S) bf16 ----------------
__global__ void vtrans(const short* __restrict__ qkv, short* __restrict__ vt) {
  __shared__ short t[32][33];
  int bh = blockIdx.z;
  int b = bh / Hn, h = bh % Hn;
  int s0 = blockIdx.x * 32, d0 = blockIdx.y * 32;
  int tx = threadIdx.x, ty = threadIdx.y;
#pragma unroll
  for (int i = 0; i < 4; i++)
    t[ty + i * 8][tx] =
        qkv[(size_t)(b * Sn + s0 + ty + i * 8) * (3 * Dn) + 2 * Dn + h * DKn + d0 + tx];
  __syncthreads();
#pragma unroll
  for (int i = 0; i < 4; i++)
    vt[(size_t)(bh * DKn + d0 + ty + i * 8) * Sn + s0 + tx] = t[tx][ty + i * 8];
}

// ---------------- fused attention: 8 waves x 16 q-rows = 128-row Q-tile ------------
// One K/V staging (16KB) feeds 128 q-rows -> half the block-iterations of the 4-wave
// version. K tile [64 kc][64 dk] / V^T tile [64 dk][64 kc] in LDS (dbuf, swizzled
// source, swizzled read). Bias is pre-scaled masked bf16; regs prefetched 1 iter
// ahead. Static-max softcap softmax -> no rescale, no cross-wave combine.
__global__ __launch_bounds__(512, 2) void attn_kernel(const short* __restrict__ qkv,
                                                      const short* __restrict__ vt,
                                                      const short* __restrict__ biasb,
                                                      short* __restrict__ o) {
  __shared__ __align__(16) short Ks[2][4096];
  __shared__ __align__(16) short Vs[2][4096];
  __shared__ __align__(16) short plds[8][16][72];
  int bh = blockIdx.x;
  int qt = 15 - (int)blockIdx.y;  // longest-first dispatch
  int b = bh / Hn, h = bh - b * Hn;
  int tid = threadIdx.x, w = tid >> 6, lane = tid & 63, g = lane >> 4, lt = lane & 15;
  int q0 = qt * 128 + w * 16;
  const short* qbase = qkv + (size_t)(b * Sn + q0 + lt) * (3 * Dn) + h * DKn;
  s16x8 qf0 = *(const s16x8*)(qbase + g * 8);
  s16x8 qf1 = *(const s16x8*)(qbase + 32 + g * 8);
  // staging: 512 threads, 1 chunk each: row = tid>>3 (0..63), chunk (tid&7)^(row&7)
  int srow = tid >> 3, scc = (tid & 7) ^ (srow & 7);
  const short* ksrc = qkv + (size_t)(b * Sn + srow) * (3 * Dn) + Dn + h * DKn + scc * 8;
  const short* vsrc = vt + ((size_t)bh * DKn + srow) * Sn + scc * 8;
  int sw = lt & 7;
  int ch0 = (g ^ sw) * 8, ch1 = ((4 + g) ^ sw) * 8;
  const short* bbase = biasb + ((size_t)b * Sn + q0 + g * 4) * Sn + lt;
  f32x4 oacc[4] = {};
  float lsum[4] = {0.f, 0.f, 0.f, 0.f};
  // prologue: stage tile 0 + bias regs for t=0
  g2lds16(ksrc, &Ks[0][tid * 8]);
  g2lds16(vsrc, &Vs[0][tid * 8]);
  short sb[16];
#pragma unroll
  for (int c = 0; c < 4; c++)
#pragma unroll
    for (int r = 0; r < 4; r++) sb[c * 4 + r] = bbase[(size_t)r * Sn + c * 16];
  __syncthreads();
  int nt = 2 * qt + 2;
  for (int t = 0; t < nt; t++) {
    int cur = t & 1;
    int kc0 = t * 64;
    if (t + 1 < nt) {  // prefetch next K/V tile into other buffer
      g2lds16(ksrc + (size_t)(kc0 + 64) * (3 * Dn), &Ks[cur ^ 1][tid * 8]);
      g2lds16(vsrc + kc0 + 64, &Vs[cur ^ 1][tid * 8]);
    }
    // prefetch bias regs for t+1 (consumed next iteration -> latency hidden)
    short sbn[16];
    if (t + 1 < nt) {
      int kn = kc0 + 64;
#pragma unroll
      for (int c = 0; c < 4; c++)
#pragma unroll
        for (int r = 0; r < 4; r++) sbn[c * 4 + r] = bbase[(size_t)r * Sn + kn + c * 16];
    }
    // K fragments from LDS (swizzled)
    s16x8 kf[4][2];
#pragma unroll
    for (int c = 0; c < 4; c++) {
      kf[c][0] = *(const s16x8*)&Ks[cur][(c * 16 + lt) * 64 + ch0];
      kf[c][1] = *(const s16x8*)&Ks[cur][(c * 16 + lt) * 64 + ch1];
    }
    f32x4 s[4] = {};
#pragma unroll
    for (int c = 0; c < 4; c++) {
      s[c] = MFMA(qf0, kf[c][0], s[c]);
      s[c] = MFMA(qf1, kf[c][1], s[c]);
    }
    // V fragments from LDS
    s16x8 vf[4][2];
#pragma unroll
    for (int dt = 0; dt < 4; dt++) {
      vf[dt][0] = *(const s16x8*)&Vs[cur][(dt * 16 + lt) * 64 + ch0];
      vf[dt][1] = *(const s16x8*)&Vs[cur][(dt * 16 + lt) * 64 + ch1];
    }
    // softcap softmax, static max 30: p = exp2(C3 / (1 + exp2(s*C1 + biasb)))
    // masked entries have biasb = -1e30 -> p = exp2(C3) ~ 1e-26 ~ 0
#pragma unroll
    for (int c = 0; c < 4; c++) {
#pragma unroll
      for (int r = 0; r < 4; r++) {
        float targ = fmaf(s[c][r], C1f, bf2f(sb[c * 4 + r]));
        float e = __builtin_amdgcn_exp2f(targ);
        float u = __builtin_amdgcn_rcpf(1.0f + e);
        float p = __builtin_amdgcn_exp2f(C3f * u);
        lsum[r] += p;
        plds[w][g * 4 + r][c * 16 + lt] = f2bf(p);
      }
    }
    // P round-trip (C-layout -> A-layout) and PV
    s16x8 pf0 = *(const s16x8*)&plds[w][lt][g * 8];
    s16x8 pf1 = *(const s16x8*)&plds[w][lt][32 + g * 8];
#pragma unroll
    for (int dt = 0; dt < 4; dt++) {
      oacc[dt] = MFMA(pf0, vf[dt][0], oacc[dt]);
      oacc[dt] = MFMA(pf1, vf[dt][1], oacc[dt]);
    }
    __syncthreads();
    if (t + 1 < nt) {
#pragma unroll
      for (int i = 0; i < 16; i++) sb[i] = sbn[i];
    }
  }
  // normalize and store (wave owns its rows completely)
  float inv[4];
#pragma unroll
  for (int r = 0; r < 4; r++) {
    float l = lsum[r];
    l += __shfl_xor(l, 1);
    l += __shfl_xor(l, 2);
    l += __shfl_xor(l, 4);
    l += __shfl_xor(l, 8);
    inv[r] = __builtin_amdgcn_rcpf(l);
  }
  short* obase = o + (size_t)(b * Sn + q0 + g * 4) * Dn + h * DKn + lt;
#pragma unroll
  for (int dt = 0; dt < 4; dt++)
#pragma unroll
    for (int r = 0; r < 4; r++) obase[(size_t)r * Dn + dt * 16] = f2bf(oacc[dt][r] * inv[r]);
}

// ---------------- launch ----------------
extern "C" void kernel_launch(void* const* d_in, const int* in_sizes, int n_in,
                              void* d_out, int out_size, void* d_ws, size_t ws_size,
                              hipStream_t stream) {
  const float* x = (const float*)d_in[0];
  const float* bias = (const float*)d_in[1];
  // d_in[2] = attn_mask (exact causal tril) -> baked into biasb
  const float* Wq = (const float*)d_in[3];
  const float* Wk = (const float*)d_in[4];
  const float* Wv = (const float*)d_in[5];
  const float* Wo = (const float*)d_in[6];
  const float* W1 = (const float*)d_in[7];
  const float* W2 = (const float*)d_in[8];
  const float* g1 = (const float*)d_in[9];
  const float* b1 = (const float*)d_in[10];
  const float* g2 = (const float*)d_in[11];
  const float* b2 = (const float*)d_in[12];
  float* out = (float*)d_out;
  char* ws = (char*)d_ws;

  short* wqkv_t = (short*)(ws + 0);          // 2304x768 bf16
  short* wo_t = (short*)(ws + 3538944);      // 768x768
  short* w1_t = (short*)(ws + 4718592);      // 3072x768
  short* w2_t = (short*)(ws + 9437184);      // 768x3072
  short* hb = (short*)(ws + 14155776);       // 4096x768 bf16 (reused as h2b)
  float* hf = (float*)(ws + 20447232);       // 4096x768 f32  (reused as h2f)
  short* qkv = (short*)(ws + 33030144);      // 4096x2304 bf16 (region reused by a1)
  short* a1 = qkv;
  short* vt = (short*)(ws + 58195968);       // 24x64x2048 bf16 (region reused by x1 f32)
  float* x1 = (float*)(ws + 58195968);
  short* o_ = (short*)(ws + 70778880);       // 4096x768 bf16
  short* biasb = (short*)(ws + 77070336);    // 2x2048x2048 bf16 (masked, pre-scaled)
  short* h2b = hb;
  float* h2f = hf;

  dim3 tb(32, 8);
  bias_prep<<<4096, 256, 0, stream>>>(bias, biasb);
  wtrans3<<<dim3(24, 24, 3), tb, 0, stream>>>(Wq, Wk, Wv, wqkv_t);
  wtrans<<<dim3(24, 24), tb, 0, stream>>>(Wo, wo_t, Dn, Dn);
  wtrans<<<dim3(96, 24), tb, 0, stream>>>(W1, w1_t, Dn, DFn);
  wtrans<<<dim3(24, 96), tb, 0, stream>>>(W2, w2_t, DFn, Dn);

  ln_kernel<<<Mrows, 256, 0, stream>>>(x, g1, b1, hb, hf);

  gemm_bt<0><<<dim3(32, 18), 256, 0, stream>>>(hb, wqkv_t, qkv, nullptr, nullptr,
                                               Mrows, 3 * Dn, Dn);
  vtrans<<<dim3(64, 2, Bn * Hn), tb, 0, stream>>>(qkv, vt);
  attn_kernel<<<dim3(24, 16), 512, 0, stream>>>(qkv, vt, biasb, o_);

  gemm64<2><<<dim3(64, 12), 256, 0, stream>>>(o_, wo_t, nullptr, hf, x1,
                                              Mrows, Dn, Dn);
  ln_kernel<<<Mrows, 256, 0, stream>>>(x1, g2, b2, h2b, h2f);
  gemm_bt<1><<<dim3(32, 24), 256, 0, stream>>>(h2b, w1_t, a1, nullptr, nullptr,
                                               Mrows, DFn, Dn);
  gemm64<2><<<dim3(64, 12), 256, 0, stream>>>(a1, w2_t, nullptr, h2f, out,
                                              Mrows, Dn, DFn);
}

// Round 9
// 336.862 us; speedup vs baseline: 1.0091x; 1.0063x over previous
//
#include <hip/hip_runtime.h>
#include <hip/hip_bf16.h>
#include <cstdint>

// ---------------- constants ----------------
#define Bn 2
#define Sn 2048
#define Dn 768
#define Hn 12
#define DKn 64
#define DFn 3072
#define Mrows 4096   // B*S

typedef float f32x4 __attribute__((ext_vector_type(4)));
typedef __bf16 bf16x8 __attribute__((ext_vector_type(8)));
typedef short s16x8 __attribute__((ext_vector_type(8)));
typedef short s16x4 __attribute__((ext_vector_type(4)));

__device__ __forceinline__ f32x4 MFMA(s16x8 a, s16x8 b, f32x4 c) {
  return __builtin_amdgcn_mfma_f32_16x16x32_bf16(
      __builtin_bit_cast(bf16x8, a), __builtin_bit_cast(bf16x8, b), c, 0, 0, 0);
}

__device__ __forceinline__ void g2lds16(const void* g, void* l) {
  __builtin_amdgcn_global_load_lds(
      (__attribute__((address_space(1))) void*)(g),
      (__attribute__((address_space(3))) void*)(l), 16, 0, 0);
}

__device__ __forceinline__ short f2bf(float f) {
  unsigned u = __builtin_bit_cast(unsigned, f);
  unsigned r = (u + 0x7fffu + ((u >> 16) & 1u)) >> 16;
  return (short)r;
}

__device__ __forceinline__ float bf2f(short s) {
  unsigned u = ((unsigned)(unsigned short)s) << 16;
  return __builtin_bit_cast(float, u);
}

#define C1f 0.0120224586f   // 0.125/15*log2(e)
#define C2f 0.0961796722f   // (1/15)*log2(e)
#define C3f -86.5617013f    // -60*log2(e)

// ---------------- bias prep: biasb = bf16(bias*C2), masked -> -1e30 ----------------
__global__ __launch_bounds__(256) void bias_prep(const float* __restrict__ bias,
                                                 short* __restrict__ biasb) {
  int gid = blockIdx.x * 256 + threadIdx.x;
  size_t i8 = (size_t)gid * 8;
  int q = (int)((i8 >> 11) & 2047);
  int k0 = (int)(i8 & 2047);
  f32x4 v0 = *(const f32x4*)(bias + i8);
  f32x4 v1 = *(const f32x4*)(bias + i8 + 4);
  s16x8 o;
#pragma unroll
  for (int j = 0; j < 4; j++) o[j] = (k0 + j <= q) ? f2bf(v0[j] * C2f) : f2bf(-1e30f);
#pragma unroll
  for (int j = 0; j < 4; j++) o[4 + j] = (k0 + 4 + j <= q) ? f2bf(v1[j] * C2f) : f2bf(-1e30f);
  *(s16x8*)(biasb + i8) = o;
}

// ---------------- weight transpose: in (R,C) f32 -> out (C,R) bf16 ----------------
__global__ void wtrans(const float* __restrict__ in, short* __restrict__ out, int R, int C) {
  __shared__ float t[32][33];
  int c0 = blockIdx.x * 32, r0 = blockIdx.y * 32;
  int tx = threadIdx.x, ty = threadIdx.y;  // 32 x 8
#pragma unroll
  for (int i = 0; i < 4; i++) t[ty + i * 8][tx] = in[(size_t)(r0 + ty + i * 8) * C + c0 + tx];
  __syncthreads();
#pragma unroll
  for (int i = 0; i < 4; i++) out[(size_t)(c0 + ty + i * 8) * R + r0 + tx] = f2bf(t[tx][ty + i * 8]);
}

// 3-in-1 transpose for Wq/Wk/Wv -> contiguous wqkv_t
__global__ void wtrans3(const float* __restrict__ Wq, const float* __restrict__ Wk,
                        const float* __restrict__ Wv, short* __restrict__ out) {
  __shared__ float t[32][33];
  int z = blockIdx.z;
  const float* in = (z == 0) ? Wq : (z == 1) ? Wk : Wv;
  short* o = out + (size_t)z * Dn * Dn;
  int c0 = blockIdx.x * 32, r0 = blockIdx.y * 32;
  int tx = threadIdx.x, ty = threadIdx.y;
#pragma unroll
  for (int i = 0; i < 4; i++) t[ty + i * 8][tx] = in[(size_t)(r0 + ty + i * 8) * Dn + c0 + tx];
  __syncthreads();
#pragma unroll
  for (int i = 0; i < 4; i++) o[(size_t)(c0 + ty + i * 8) * Dn + r0 + tx] = f2bf(t[tx][ty + i * 8]);
}

// ---------------- layernorm: x f32 (row of 768) -> h bf16 + h f32 ----------------
__global__ __launch_bounds__(256) void ln_kernel(const float* __restrict__ x,
                                                 const float* __restrict__ g,
                                                 const float* __restrict__ b,
                                                 short* __restrict__ hb,
                                                 float* __restrict__ hf) {
  int row = blockIdx.x;
  const float* xr = x + (size_t)row * Dn;
  int tid = threadIdx.x;
  float v[3];
  float s = 0.f, ss = 0.f;
#pragma unroll
  for (int i = 0; i < 3; i++) {
    v[i] = xr[tid + i * 256];
    s += v[i];
    ss += v[i] * v[i];
  }
#pragma unroll
  for (int m = 1; m < 64; m <<= 1) {
    s += __shfl_xor(s, m);
    ss += __shfl_xor(ss, m);
  }
  __shared__ float red[8];
  int w = tid >> 6, lane = tid & 63;
  if (lane == 0) { red[w] = s; red[4 + w] = ss; }
  __syncthreads();
  s = red[0] + red[1] + red[2] + red[3];
  ss = red[4] + red[5] + red[6] + red[7];
  float mean = s * (1.0f / Dn);
  float var = ss * (1.0f / Dn) - mean * mean;
  float rs = rsqrtf(var + 1e-5f);
#pragma unroll
  for (int i = 0; i < 3; i++) {
    int c = tid + i * 256;
    float h = (v[i] - mean) * rs * g[c] + b[c];
    hb[(size_t)row * Dn + c] = f2bf(h);
    hf[(size_t)row * Dn + c] = h;
  }
}

// ---- layernorm over sum of 4 bf16 partials + residual: x1 = Σp + hf; LN -> h2b,h2f
__global__ __launch_bounds__(256) void ln_fuse4(const short* __restrict__ p0,
                                                const short* __restrict__ p1,
                                                const short* __restrict__ p2,
                                                const short* __restrict__ p3,
                                                const float* __restrict__ hfin,
                                                const float* __restrict__ g,
                                                const float* __restrict__ b,
                                                short* __restrict__ hb,
                                                float* __restrict__ hfout) {
  int row = blockIdx.x;
  size_t base = (size_t)row * Dn;
  int tid = threadIdx.x;
  float v[3];
  float s = 0.f, ss = 0.f;
#pragma unroll
  for (int i = 0; i < 3; i++) {
    size_t idx = base + tid + i * 256;
    float x = bf2f(p0[idx]) + bf2f(p1[idx]) + bf2f(p2[idx]) + bf2f(p3[idx]) + hfin[idx];
    v[i] = x;
    s += x;
    ss += x * x;
  }
#pragma unroll
  for (int m = 1; m < 64; m <<= 1) {
    s += __shfl_xor(s, m);
    ss += __shfl_xor(ss, m);
  }
  __shared__ float red[8];
  int w = tid >> 6, lane = tid & 63;
  if (lane == 0) { red[w] = s; red[4 + w] = ss; }
  __syncthreads();
  s = red[0] + red[1] + red[2] + red[3];
  ss = red[4] + red[5] + red[6] + red[7];
  float mean = s * (1.0f / Dn);
  float var = ss * (1.0f / Dn) - mean * mean;
  float rs = rsqrtf(var + 1e-5f);
#pragma unroll
  for (int i = 0; i < 3; i++) {
    int c = tid + i * 256;
    float h = (v[i] - mean) * rs * g[c] + b[c];
    hb[base + c] = f2bf(h);
    hfout[base + c] = h;
  }
}

// ---- final: out = Σ 4 bf16 partials + h2f (f32) ----
__global__ __launch_bounds__(256) void final_add(const short* __restrict__ q0,
                                                 const short* __restrict__ q1,
                                                 const short* __restrict__ q2,
                                                 const short* __restrict__ q3,
                                                 const float* __restrict__ h2f,
                                                 float* __restrict__ out) {
  size_t i8 = ((size_t)blockIdx.x * 256 + threadIdx.x) * 8;
  s16x8 a = *(const s16x8*)(q0 + i8);
  s16x8 b = *(const s16x8*)(q1 + i8);
  s16x8 c = *(const s16x8*)(q2 + i8);
  s16x8 d = *(const s16x8*)(q3 + i8);
  f32x4 h0 = *(const f32x4*)(h2f + i8);
  f32x4 h1 = *(const f32x4*)(h2f + i8 + 4);
  f32x4 o0, o1;
#pragma unroll
  for (int j = 0; j < 4; j++)
    o0[j] = bf2f(a[j]) + bf2f(b[j]) + bf2f(c[j]) + bf2f(d[j]) + h0[j];
#pragma unroll
  for (int j = 0; j < 4; j++)
    o1[j] = bf2f(a[4 + j]) + bf2f(b[4 + j]) + bf2f(c[4 + j]) + bf2f(d[4 + j]) + h1[j];
  *(f32x4*)(out + i8) = o0;
  *(f32x4*)(out + i8 + 4) = o1;
}

// ---------------- 128x128 bf16 GEMM, BK=32, single-buffer, swizzled LDS -----------
// C = A @ Bt^T (row-major A: M x lda, Bt: N x lda). Loop over Kspan columns starting
// at blockIdx.z * Kspan. Output pointer selected by blockIdx.z (split-K partials).
// EPI 0: C bf16   EPI 1: gelu -> C bf16
template <int EPI>
__global__ __launch_bounds__(256) void gemm_bt(const short* __restrict__ A,
                                               const short* __restrict__ Bt,
                                               short* __restrict__ c0p,
                                               short* __restrict__ c1p,
                                               short* __restrict__ c2p,
                                               short* __restrict__ c3p,
                                               int M, int N, int Kspan, int lda) {
  __shared__ __align__(16) short As[4096];
  __shared__ __align__(16) short Bs[4096];
  int z = blockIdx.z;
  const short* Ab = A + (size_t)z * Kspan;
  const short* Bb = Bt + (size_t)z * Kspan;
  short* Cb = (z == 0) ? c0p : (z == 1) ? c1p : (z == 2) ? c2p : c3p;
  int tid = threadIdx.x;
  int lane = tid & 63, w = tid >> 6, g = lane >> 4, lt = lane & 15;
  int wr = w >> 1, wc = w & 1;
  int m0 = blockIdx.x * 128, n0 = blockIdx.y * 128;
  // staging: chunk i = h*256+tid -> row i>>2 (h=1: +64), src chunk (i&3)^((row>>1)&3)
  int r0 = tid >> 2, c4 = tid & 3;
  int cc = c4 ^ ((r0 >> 1) & 3);
  const short* Ag0 = Ab + (size_t)(m0 + r0) * lda + cc * 8;
  const short* Ag1 = Ab + (size_t)(m0 + r0 + 64) * lda + cc * 8;
  const short* Bg0 = Bb + (size_t)(n0 + r0) * lda + cc * 8;
  const short* Bg1 = Bb + (size_t)(n0 + r0 + 64) * lda + cc * 8;
  int swr = (lt >> 1) & 3;
  int cfrag = (g ^ swr) * 8;  // swizzled k-chunk offset (shorts) for fragment reads
  f32x4 acc[4][4] = {};
  for (int k0 = 0; k0 < Kspan; k0 += 32) {
    g2lds16(Ag0 + k0, &As[tid * 8]);
    g2lds16(Ag1 + k0, &As[2048 + tid * 8]);
    g2lds16(Bg0 + k0, &Bs[tid * 8]);
    g2lds16(Bg1 + k0, &Bs[2048 + tid * 8]);
    __syncthreads();
    s16x8 af[4], bfr[4];
#pragma unroll
    for (int i = 0; i < 4; i++) {
      af[i] = *(const s16x8*)&As[(wr * 64 + i * 16 + lt) * 32 + cfrag];
      bfr[i] = *(const s16x8*)&Bs[(wc * 64 + i * 16 + lt) * 32 + cfrag];
    }
#pragma unroll
    for (int mi = 0; mi < 4; mi++)
#pragma unroll
      for (int ni = 0; ni < 4; ni++) acc[mi][ni] = MFMA(af[mi], bfr[ni], acc[mi][ni]);
    __syncthreads();
  }
#pragma unroll
  for (int mi = 0; mi < 4; mi++) {
    int m = m0 + wr * 64 + mi * 16 + g * 4;
#pragma unroll
    for (int ni = 0; ni < 4; ni++) {
      int n = n0 + wc * 64 + ni * 16 + lt;
#pragma unroll
      for (int r = 0; r < 4; r++) {
        float v = acc[mi][ni][r];
        size_t idx = (size_t)(m + r) * N + n;
        if constexpr (EPI == 0) {
          Cb[idx] = f2bf(v);
        } else {
          float ge = 0.5f * v * (1.0f + erff(v * 0.70710678f));
          Cb[idx] = f2bf(ge);
        }
      }
    }
  }
}

// ---------------- V transpose: qkv v-cols -> vt (B,H,DK,S) bf16 ----------------
__global__ void vtrans(const short* __restrict__ qkv, short* __restrict__ vt) {
  __shared__ short t[32][33];
  int bh = blockIdx.z;
  int b = bh / Hn, h = bh % Hn;
  int s0 = blockIdx.x * 32, d0 = blockIdx.y * 32;
  int tx = threadIdx.x, ty = threadIdx.y;
#pragma unroll
  for (int i = 0; i < 4; i++)
    t[ty + i * 8][tx] =
        qkv[(size_t)(b * Sn + s0 + ty + i * 8) * (3 * Dn) + 2 * Dn + h * DKn + d0 + tx];
  __syncthreads();
#pragma unroll
  for (int i = 0; i < 4; i++)
    vt[(size_t)(bh * DKn + d0 + ty + i * 8) * Sn + s0 + tx] = t[tx][ty + i * 8];
}

// ---------------- fused attention: 64-row Q-tile, LDS K/V dbuf, pipelined bias -----
// (round-5 proven version) Bias is pre-scaled bf16 with mask baked in.
__global__ __launch_bounds__(256, 3) void attn_kernel(const short* __restrict__ qkv,
                                                      const short* __restrict__ vt,
                                                      const short* __restrict__ biasb,
                                                      short* __restrict__ o) {
  __shared__ __align__(16) short Ks[2][4096];
  __shared__ __align__(16) short Vs[2][4096];
  __shared__ __align__(16) short plds[4][16][72];
  int bh = blockIdx.x;
  int by = blockIdx.y;
  int qt = (by & 1) ? (31 - (by >> 1)) : (by >> 1);  // snake: mix long/short blocks
  int b = bh / Hn, h = bh - b * Hn;
  int tid = threadIdx.x, w = tid >> 6, lane = tid & 63, g = lane >> 4, lt = lane & 15;
  int q0 = qt * 64 + w * 16;
  const short* qbase = qkv + (size_t)(b * Sn + q0 + lt) * (3 * Dn) + h * DKn;
  s16x8 qf0 = *(const s16x8*)(qbase + g * 8);
  s16x8 qf1 = *(const s16x8*)(qbase + 32 + g * 8);
  int sr0 = tid >> 3, scc = (tid & 7) ^ (sr0 & 7);
  const short* kseg = qkv + (size_t)b * Sn * (3 * Dn) + Dn + h * DKn;
  const short* ksrc0 = kseg + (size_t)sr0 * (3 * Dn) + scc * 8;
  const short* ksrc1 = kseg + (size_t)(sr0 + 32) * (3 * Dn) + scc * 8;
  const short* vseg = vt + (size_t)bh * DKn * Sn;
  const short* vsrc0 = vseg + (size_t)sr0 * Sn + scc * 8;
  const short* vsrc1 = vseg + (size_t)(sr0 + 32) * Sn + scc * 8;
  int sw = lt & 7;
  int ch0 = (g ^ sw) * 8, ch1 = ((4 + g) ^ sw) * 8;
  const short* bbase = biasb + ((size_t)b * Sn + q0 + g * 4) * Sn + lt;
  f32x4 oacc[4] = {};
  float lsum[4] = {0.f, 0.f, 0.f, 0.f};
  // prologue: stage tile 0 + bias regs for t=0
  g2lds16(ksrc0, &Ks[0][tid * 8]);
  g2lds16(ksrc1, &Ks[0][2048 + tid * 8]);
  g2lds16(vsrc0, &Vs[0][tid * 8]);
  g2lds16(vsrc1, &Vs[0][2048 + tid * 8]);
  short sb[16];
#pragma unroll
  for (int c = 0; c < 4; c++)
#pragma unroll
    for (int r = 0; r < 4; r++) sb[c * 4 + r] = bbase[(size_t)r * Sn + c * 16];
  __syncthreads();
  for (int t = 0; t <= qt; t++) {
    int cur = t & 1;
    int kc0 = t * 64;
    if (t < qt) {  // prefetch next K/V tile into other buffer
      size_t koff = (size_t)(kc0 + 64) * (3 * Dn);
      g2lds16(ksrc0 + koff, &Ks[cur ^ 1][tid * 8]);
      g2lds16(ksrc1 + koff, &Ks[cur ^ 1][2048 + tid * 8]);
      g2lds16(vsrc0 + kc0 + 64, &Vs[cur ^ 1][tid * 8]);
      g2lds16(vsrc1 + kc0 + 64, &Vs[cur ^ 1][2048 + tid * 8]);
    }
    // prefetch bias regs for t+1 (consumed next iteration -> latency hidden)
    short sbn[16];
    if (t < qt) {
      int kn = kc0 + 64;
#pragma unroll
      for (int c = 0; c < 4; c++)
#pragma unroll
        for (int r = 0; r < 4; r++) sbn[c * 4 + r] = bbase[(size_t)r * Sn + kn + c * 16];
    }
    // K fragments from LDS (swizzled)
    s16x8 kf[4][2];
#pragma unroll
    for (int c = 0; c < 4; c++) {
      kf[c][0] = *(const s16x8*)&Ks[cur][(c * 16 + lt) * 64 + ch0];
      kf[c][1] = *(const s16x8*)&Ks[cur][(c * 16 + lt) * 64 + ch1];
    }
    f32x4 s[4] = {};
#pragma unroll
    for (int c = 0; c < 4; c++) {
      s[c] = MFMA(qf0, kf[c][0], s[c]);
      s[c] = MFMA(qf1, kf[c][1], s[c]);
    }
    // V fragments from LDS
    s16x8 vf[4][2];
#pragma unroll
    for (int dt = 0; dt < 4; dt++) {
      vf[dt][0] = *(const s16x8*)&Vs[cur][(dt * 16 + lt) * 64 + ch0];
      vf[dt][1] = *(const s16x8*)&Vs[cur][(dt * 16 + lt) * 64 + ch1];
    }
    // softcap softmax, static max 30: p = exp2(C3 / (1 + exp2(s*C1 + biasb)))
#pragma unroll
    for (int c = 0; c < 4; c++) {
#pragma unroll
      for (int r = 0; r < 4; r++) {
        float targ = fmaf(s[c][r], C1f, bf2f(sb[c * 4 + r]));
        float e = __builtin_amdgcn_exp2f(targ);
        float u = __builtin_amdgcn_rcpf(1.0f + e);
        float p = __builtin_amdgcn_exp2f(C3f * u);
        lsum[r] += p;
        plds[w][g * 4 + r][c * 16 + lt] = f2bf(p);
      }
    }
    // P round-trip (C-layout -> A-layout) and PV
    s16x8 pf0 = *(const s16x8*)&plds[w][lt][g * 8];
    s16x8 pf1 = *(const s16x8*)&plds[w][lt][32 + g * 8];
#pragma unroll
    for (int dt = 0; dt < 4; dt++) {
      oacc[dt] = MFMA(pf0, vf[dt][0], oacc[dt]);
      oacc[dt] = MFMA(pf1, vf[dt][1], oacc[dt]);
    }
    __syncthreads();
    if (t < qt) {
#pragma unroll
      for (int i = 0; i < 16; i++) sb[i] = sbn[i];
    }
  }
  // normalize and store (wave owns its rows completely)
  float inv[4];
#pragma unroll
  for (int r = 0; r < 4; r++) {
    float l = lsum[r];
    l += __shfl_xor(l, 1);
    l += __shfl_xor(l, 2);
    l += __shfl_xor(l, 4);
    l += __shfl_xor(l, 8);
    inv[r] = __builtin_amdgcn_rcpf(l);
  }
  short* obase = o + (size_t)(b * Sn + q0 + g * 4) * Dn + h * DKn + lt;
#pragma unroll
  for (int dt = 0; dt < 4; dt++)
#pragma unroll
    for (int r = 0; r < 4; r++) obase[(size_t)r * Dn + dt * 16] = f2bf(oacc[dt][r] * inv[r]);
}

// ---------------- launch ----------------
extern "C" void kernel_launch(void* const* d_in, const int* in_sizes, int n_in,
                              void* d_out, int out_size, void* d_ws, size_t ws_size,
                              hipStream_t stream) {
  const float* x = (const float*)d_in[0];
  const float* bias = (const float*)d_in[1];
  // d_in[2] = attn_mask (exact causal tril) -> baked into biasb
  const float* Wq = (const float*)d_in[3];
  const float* Wk = (const float*)d_in[4];
  const float* Wv = (const float*)d_in[5];
  const float* Wo = (const float*)d_in[6];
  const float* W1 = (const float*)d_in[7];
  const float* W2 = (const float*)d_in[8];
  const float* g1 = (const float*)d_in[9];
  const float* b1 = (const float*)d_in[10];
  const float* g2 = (const float*)d_in[11];
  const float* b2 = (const float*)d_in[12];
  float* out = (float*)d_out;
  char* ws = (char*)d_ws;

  short* wqkv_t = (short*)(ws + 0);          // 2304x768 bf16
  short* wo_t = (short*)(ws + 3538944);      // 768x768
  short* w1_t = (short*)(ws + 4718592);      // 3072x768
  short* w2_t = (short*)(ws + 9437184);      // 768x3072
  short* hb = (short*)(ws + 14155776);       // 4096x768 bf16 (reused as h2b)
  float* hf = (float*)(ws + 20447232);       // 4096x768 f32  (reused as h2f)
  short* qkv = (short*)(ws + 33030144);      // 4096x2304 bf16 (reused: Wo partials, a1)
  short* a1 = qkv;
  short* vt = (short*)(ws + 58195968);       // 24x64x2048 bf16 (reused: FFN2 p0,p1)
  short* o_ = (short*)(ws + 70778880);       // 4096x768 bf16 (reused: FFN2 p2)
  short* biasb = (short*)(ws + 77070336);    // 2x2048x2048 bf16 (reused: FFN2 p3)
  short* h2b = hb;
  float* h2f = hf;
  const int PSZ = Mrows * Dn;                // elements per partial (3145728)
  short* pW = qkv;                           // 4 Wo partials (fits qkv region exactly)
  short* pF0 = vt;
  short* pF1 = vt + PSZ;
  short* pF2 = o_;
  short* pF3 = biasb;

  dim3 tb(32, 8);
  bias_prep<<<4096, 256, 0, stream>>>(bias, biasb);
  wtrans3<<<dim3(24, 24, 3), tb, 0, stream>>>(Wq, Wk, Wv, wqkv_t);
  wtrans<<<dim3(24, 24), tb, 0, stream>>>(Wo, wo_t, Dn, Dn);
  wtrans<<<dim3(96, 24), tb, 0, stream>>>(W1, w1_t, Dn, DFn);
  wtrans<<<dim3(24, 96), tb, 0, stream>>>(W2, w2_t, DFn, Dn);

  ln_kernel<<<Mrows, 256, 0, stream>>>(x, g1, b1, hb, hf);

  gemm_bt<0><<<dim3(32, 18, 1), 256, 0, stream>>>(hb, wqkv_t, qkv, qkv, qkv, qkv,
                                                  Mrows, 3 * Dn, Dn, Dn);
  vtrans<<<dim3(64, 2, Bn * Hn), tb, 0, stream>>>(qkv, vt);
  attn_kernel<<<dim3(24, 32), 256, 0, stream>>>(qkv, vt, biasb, o_);

  // Wo: split-K x4 (Kspan 192) -> 4 bf16 partials in qkv region
  gemm_bt<0><<<dim3(32, 6, 4), 256, 0, stream>>>(o_, wo_t, pW, pW + PSZ, pW + 2 * PSZ,
                                                 pW + 3 * PSZ, Mrows, Dn, 192, Dn);
  // ln2 fused over partial sum + residual
  ln_fuse4<<<Mrows, 256, 0, stream>>>(pW, pW + PSZ, pW + 2 * PSZ, pW + 3 * PSZ,
                                      hf, g2, b2, h2b, h2f);
  // FFN1 (gelu epilogue)
  gemm_bt<1><<<dim3(32, 24, 1), 256, 0, stream>>>(h2b, w1_t, a1, a1, a1, a1,
                                                  Mrows, DFn, Dn, Dn);
  // FFN2: split-K x4 (Kspan 768) -> 4 bf16 partials in dead regions
  gemm_bt<0><<<dim3(32, 6, 4), 256, 0, stream>>>(a1, w2_t, pF0, pF1, pF2, pF3,
                                                 Mrows, Dn, 768, DFn);
  final_add<<<1536, 256, 0, stream>>>(pF0, pF1, pF2, pF3, h2f, out);
}